// Round 1
// 447.606 us; speedup vs baseline: 1.0809x; 1.0809x over previous
//
#include <hip/hip_runtime.h>
#include <hip/hip_bf16.h>

#define T_TOK 2048
#define D_DIM 2048
#define N_EXP 8
#define F_DIM 1024

typedef __attribute__((ext_vector_type(8))) short short8;
typedef __attribute__((ext_vector_type(4))) float floatx4;

__device__ __forceinline__ short f2bf(float f) {
  union { float f; unsigned u; } v; v.f = f;
  unsigned r = v.u + 0x7fffu + ((v.u >> 16) & 1u);
  return (short)(r >> 16);
}

__device__ __forceinline__ floatx4 mfma16(short8 a, short8 b, floatx4 c) {
  return __builtin_amdgcn_mfma_f32_16x16x32_bf16(a, b, c, 0, 0, 0);
}

__device__ __forceinline__ void gload16(const void* g, void* l) {
  __builtin_amdgcn_global_load_lds(
      (const __attribute__((address_space(1))) unsigned int*)g,
      (__attribute__((address_space(3))) unsigned int*)l, 16, 0, 0);
}

// ---- transpose+cvt+PACK wg/wu: [E][D][F] -> pw[((e*16+fb)*32+s)*4096 + r*64 + c]
// (fb = f>>6, r = f&63, s = d>>6, c = d&63) : each (fb,s) chunk is 8KB contiguous.
__global__ __launch_bounds__(256) void pack_wgwu(const float* __restrict__ src,
                                                 short* __restrict__ dst) {
  int fb = blockIdx.x, s = blockIdx.y, e = blockIdx.z;
  __shared__ float tile[64][65];   // [d-local][f-local]
  int tx = threadIdx.x & 63, ty = threadIdx.x >> 6;
  const float* sp = src + (size_t)e * D_DIM * F_DIM + (size_t)(s * 64) * F_DIM + fb * 64;
#pragma unroll
  for (int i = 0; i < 64; i += 4)
    tile[ty + i][tx] = sp[(size_t)(ty + i) * F_DIM + tx];
  __syncthreads();
  short* dp = dst + (size_t)((e * 16 + fb) * 32 + s) * 4096;
#pragma unroll
  for (int i = 0; i < 64; i += 4)
    dp[(ty + i) * 64 + tx] = f2bf(tile[tx][ty + i]);   // dst[r][c] = src(d=s64+c, f=fb64+r)
}

// ---- transpose+cvt+PACK wd: [E][F][D] -> pw[((e*16+nb)*16+s)*8192 + r*64 + c]
// (nb = d>>7, r = d&127, s = f>>6, c = f&63) : each (nb,s) chunk is 16KB contiguous.
__global__ __launch_bounds__(256) void pack_wd(const float* __restrict__ src,
                                               short* __restrict__ dst) {
  int nb = blockIdx.x, s = blockIdx.y, e = blockIdx.z;
  __shared__ float tile[64][129];  // [k-local][n-local]
  int tx2 = threadIdx.x & 127, ty2 = threadIdx.x >> 7;
  const float* sp = src + (size_t)e * F_DIM * D_DIM + (size_t)(s * 64) * D_DIM + nb * 128;
#pragma unroll
  for (int i = 0; i < 64; i += 2)
    tile[ty2 + i][tx2] = sp[(size_t)(ty2 + i) * D_DIM + tx2];
  __syncthreads();
  int tx = threadIdx.x & 63, ty = threadIdx.x >> 6;
  short* dp = dst + (size_t)((e * 16 + nb) * 16 + s) * 8192;
#pragma unroll
  for (int r = 0; r < 128; r += 4)
    dp[(r + ty) * 64 + tx] = f2bf(tile[tx][r + ty]);   // dst[r][c] = src(f=s64+c, d=nb128+r)
}

// ---------------- router: logits (fp32), top-2, expert lists, x -> bf16 --------------
__global__ __launch_bounds__(256) void router_kernel(
    const float* __restrict__ x, const float* __restrict__ gate_w,
    short* __restrict__ x_bf, float* __restrict__ out_logits,
    int* __restrict__ counts, int* __restrict__ tok_ids, float* __restrict__ tok_wts) {
  int t = blockIdx.x;
  int tid = threadIdx.x;
  const float* xr = x + (size_t)t * D_DIM + tid * 8;
  floatx4 xv0 = *(const floatx4*)xr;
  floatx4 xv1 = *(const floatx4*)(xr + 4);
  float xs[8];
#pragma unroll
  for (int j = 0; j < 4; j++) { xs[j] = xv0[j]; xs[4 + j] = xv1[j]; }
  union { short8 v; short s[8]; } xb;
#pragma unroll
  for (int j = 0; j < 8; j++) xb.s[j] = f2bf(xs[j]);
  *(short8*)(x_bf + (size_t)t * D_DIM + tid * 8) = xb.v;

  float p[N_EXP];
#pragma unroll
  for (int e = 0; e < N_EXP; e++) {
    const float* gw = gate_w + (size_t)e * D_DIM + tid * 8;
    floatx4 g0 = *(const floatx4*)gw;
    floatx4 g1 = *(const floatx4*)(gw + 4);
    float s = 0.f;
#pragma unroll
    for (int j = 0; j < 4; j++) s += xs[j] * g0[j] + xs[4 + j] * g1[j];
    p[e] = s;
  }
  __shared__ float red[N_EXP * 4];
  __shared__ float slog[N_EXP];
  int lane = tid & 63, wv = tid >> 6;
#pragma unroll
  for (int e = 0; e < N_EXP; e++) {
    float v = p[e];
#pragma unroll
    for (int off = 32; off > 0; off >>= 1) v += __shfl_down(v, off);
    if (lane == 0) red[e * 4 + wv] = v;
  }
  __syncthreads();
  if (tid < N_EXP) {
    float s = red[tid * 4] + red[tid * 4 + 1] + red[tid * 4 + 2] + red[tid * 4 + 3];
    slog[tid] = s;
    out_logits[(size_t)t * N_EXP + tid] = s;
  }
  __syncthreads();
  if (tid == 0) {
    float l[N_EXP];
#pragma unroll
    for (int e = 0; e < N_EXP; e++) l[e] = slog[e];
    int e0 = 0;
#pragma unroll
    for (int e = 1; e < N_EXP; e++) if (l[e] > l[e0]) e0 = e;
    int e1 = (e0 == 0) ? 1 : 0;
#pragma unroll
    for (int e = 0; e < N_EXP; e++) if (e != e0 && l[e] > l[e1]) e1 = e;
    float p1 = __expf(l[e1] - l[e0]);
    float s = 1.f + p1;
    int pos0 = atomicAdd(&counts[e0], 1);
    tok_ids[e0 * T_TOK + pos0] = t;             // k = 0
    tok_wts[e0 * T_TOK + pos0] = 1.f / s;
    int pos1 = atomicAdd(&counts[e1], 1);
    tok_ids[e1 * T_TOK + pos1] = t | (1 << 16); // k = 1
    tok_wts[e1 * T_TOK + pos1] = p1 / s;
  }
}

// ---------------- tok2row: inverse map (token,k) -> sorted h row ---------------------
__global__ __launch_bounds__(256) void tok2row_kernel(
    const int* __restrict__ counts, const int* __restrict__ tok_ids,
    int* __restrict__ tok2row) {
  int tid = threadIdx.x;
  int base = 0;
  for (int e = 0; e < N_EXP; e++) {
    int c = counts[e];
    for (int pos = tid; pos < c; pos += 256) {
      int raw = tok_ids[e * T_TOK + pos];
      tok2row[(raw & 0xFFFF) * 2 + (raw >> 16)] = base + pos;
    }
    base += c;
  }
}

// ---------------- GEMM1: 128M x 64N, BK=64, dbuf pipeline, XCD-affine ----------------
// grid: 2048 blocks; lin = fb*128 + mt*8 + e  -> e = lin&7 (XCD id%8 round-robin:
// each XCD owns one expert; A panel (~2MB) stays L2-resident, B streamed once;
// mt fastest within fb so B-chunk-sharing blocks are scheduling neighbors).
__global__ __launch_bounds__(256, 2) void gemm1_kernel(
    const short* __restrict__ x_bf,
    const short* __restrict__ pwg, const short* __restrict__ pwu,
    const int* __restrict__ counts, const int* __restrict__ tok_ids,
    const float* __restrict__ tok_wts,
    short* __restrict__ h_sorted) {
  int lin = blockIdx.x;
  int e  = lin & 7;
  int mt = (lin >> 3) & 15;
  int fb = (lin >> 7) & 15;
  int count = counts[e];
  if (mt * 128 >= count) return;
  int hb = 0;
#pragma unroll
  for (int i = 0; i < N_EXP; i++) { int c = counts[i]; if (i < e) hb += c; }

  __shared__ short sA[2][8192];    // 2 x (128 x 64)
  __shared__ short sBg[2][4096];   // 2 x (64 x 64)
  __shared__ short sBu[2][4096];   // exactly 64KB total

  int tid = threadIdx.x;
  int lane = tid & 63, wv = tid >> 6;
  int wr = wv >> 1, wc = wv & 1;
  int l16 = lane & 15, qd = lane >> 4;
  int lr = lane >> 3, lc = lane & 7;
  int csw8 = (lc ^ lr) * 8;   // XOR swizzle: LDS[row][pos] holds chunk pos^(row&7)

  int offA[4], offB[2];
#pragma unroll
  for (int it = 0; it < 4; it++) {
    int r = wv * 32 + it * 8 + lr;
    int raw = (mt * 128 + r < count) ? tok_ids[e * T_TOK + mt * 128 + r] : 0;
    offA[it] = (raw & 0xFFFF) * D_DIM + csw8;
  }
#pragma unroll
  for (int it = 0; it < 2; it++)
    offB[it] = (wv * 16 + it * 8 + lr) * 64 + csw8;   // within packed 8KB chunk
  const short* pBg = pwg + (size_t)((e * 16 + fb) * 32) * 4096;
  const short* pBu = pwu + (size_t)((e * 16 + fb) * 32) * 4096;

  floatx4 accG[4][2] = {};
  floatx4 accU[4][2] = {};
  int sw = l16 & 7;
  int rAo  = (wr * 64 + l16) * 64;
  int rBo  = (wc * 32 + l16) * 64;

  // prologue: stage tile 0 into buffer 0
#pragma unroll
  for (int it = 0; it < 4; it++)
    gload16(x_bf + offA[it], &sA[0][wv * 2048 + it * 512]);
#pragma unroll
  for (int it = 0; it < 2; it++) {
    gload16(pBg + offB[it], &sBg[0][wv * 1024 + it * 512]);
    gload16(pBu + offB[it], &sBu[0][wv * 1024 + it * 512]);
  }

  int cur = 0;
  for (int s = 0; s < D_DIM / 64; s++) {
    __syncthreads();   // drains vmcnt: buf[cur] staged; buf[cur^1] free to overwrite
    if (s + 1 < D_DIM / 64) {
      int nxt = cur ^ 1;
#pragma unroll
      for (int it = 0; it < 4; it++)
        gload16(x_bf + offA[it] + (s + 1) * 64, &sA[nxt][wv * 2048 + it * 512]);
#pragma unroll
      for (int it = 0; it < 2; it++) {
        gload16(pBg + (size_t)(s + 1) * 4096 + offB[it], &sBg[nxt][wv * 1024 + it * 512]);
        gload16(pBu + (size_t)(s + 1) * 4096 + offB[it], &sBu[nxt][wv * 1024 + it * 512]);
      }
    }
    const short* rA  = &sA[cur][rAo];
    const short* rBg = &sBg[cur][rBo];
    const short* rBu = &sBu[cur][rBo];
#pragma unroll
    for (int kk = 0; kk < 2; kk++) {
      short8 a[4], bg[2], bu[2];
      int c = ((kk * 4 + qd) ^ sw) * 8;
#pragma unroll
      for (int mi = 0; mi < 4; mi++) a[mi] = *(const short8*)(rA + mi * 16 * 64 + c);
#pragma unroll
      for (int nj = 0; nj < 2; nj++) {
        bg[nj] = *(const short8*)(rBg + nj * 16 * 64 + c);
        bu[nj] = *(const short8*)(rBu + nj * 16 * 64 + c);
      }
#pragma unroll
      for (int mi = 0; mi < 4; mi++)
#pragma unroll
        for (int nj = 0; nj < 2; nj++) {
          accG[mi][nj] = mfma16(a[mi], bg[nj], accG[mi][nj]);
          accU[mi][nj] = mfma16(a[mi], bu[nj], accU[mi][nj]);
        }
    }
    cur ^= 1;
  }

#pragma unroll
  for (int mi = 0; mi < 4; mi++)
#pragma unroll
    for (int r = 0; r < 4; r++) {
      int rowl = wr * 64 + mi * 16 + qd * 4 + r;
      if (mt * 128 + rowl < count) {
        float wt = tok_wts[e * T_TOK + mt * 128 + rowl];
        short* hdst = h_sorted + (size_t)(hb + mt * 128 + rowl) * F_DIM
                    + fb * 64 + wc * 32 + l16;
#pragma unroll
        for (int nj = 0; nj < 2; nj++) {
          float g = accG[mi][nj][r], u = accU[mi][nj][r];
          float sg = g / (1.f + __expf(-g));
          hdst[nj * 16] = f2bf(sg * u * wt);
        }
      }
    }
}

// ---------------- GEMM2: 128x128, BK=64, dbuf pipeline, XCD-affine -------------------
__global__ __launch_bounds__(256, 2) void gemm2_kernel(
    const short* __restrict__ h_sorted, const short* __restrict__ pwd,
    const int* __restrict__ counts,
    float* __restrict__ y_sorted) {
  int lin = blockIdx.x;
  int e  = lin & 7;
  int mt = (lin >> 3) & 15;
  int nb = (lin >> 7) & 15;
  int count = counts[e];
  if (mt * 128 >= count) return;
  int hb = 0;
#pragma unroll
  for (int i = 0; i < N_EXP; i++) { int c = counts[i]; if (i < e) hb += c; }

  __shared__ short sA[2][8192];
  __shared__ short sB[2][8192];   // exactly 64KB total

  int tid = threadIdx.x;
  int lane = tid & 63, wv = tid >> 6;
  int wr = wv >> 1, wc = wv & 1;
  int l16 = lane & 15, qd = lane >> 4;
  int lr = lane >> 3, lc = lane & 7;
  int csw8 = (lc ^ lr) * 8;

  int offA[4], offB[4];
#pragma unroll
  for (int it = 0; it < 4; it++) {
    int r = wv * 32 + it * 8 + lr;
    offA[it] = (hb + mt * 128 + r) * F_DIM + csw8;     // contiguous sorted rows
    offB[it] = r * 64 + csw8;                          // within packed 16KB chunk
  }
  const short* pB = pwd + (size_t)((e * 16 + nb) * 16) * 8192;

  floatx4 acc[4][4] = {};
  int sw = l16 & 7;
  int rAo = (wr * 64 + l16) * 64;
  int rBo = (wc * 64 + l16) * 64;

  // prologue: stage tile 0 into buffer 0
#pragma unroll
  for (int it = 0; it < 4; it++) {
    gload16(h_sorted + offA[it], &sA[0][wv * 2048 + it * 512]);
    gload16(pB + offB[it], &sB[0][wv * 2048 + it * 512]);
  }

  int cur = 0;
  for (int s = 0; s < F_DIM / 64; s++) {
    __syncthreads();
    if (s + 1 < F_DIM / 64) {
      int nxt = cur ^ 1;
#pragma unroll
      for (int it = 0; it < 4; it++) {
        gload16(h_sorted + offA[it] + (s + 1) * 64, &sA[nxt][wv * 2048 + it * 512]);
        gload16(pB + (size_t)(s + 1) * 8192 + offB[it], &sB[nxt][wv * 2048 + it * 512]);
      }
    }
    const short* rA = &sA[cur][rAo];
    const short* rB = &sB[cur][rBo];
#pragma unroll
    for (int kk = 0; kk < 2; kk++) {
      short8 a[4], b[4];
      int c = ((kk * 4 + qd) ^ sw) * 8;
#pragma unroll
      for (int mi = 0; mi < 4; mi++) a[mi] = *(const short8*)(rA + mi * 16 * 64 + c);
#pragma unroll
      for (int nj = 0; nj < 4; nj++) b[nj] = *(const short8*)(rB + nj * 16 * 64 + c);
#pragma unroll
      for (int mi = 0; mi < 4; mi++)
#pragma unroll
        for (int nj = 0; nj < 4; nj++)
          acc[mi][nj] = mfma16(a[mi], b[nj], acc[mi][nj]);
    }
    cur ^= 1;
  }

#pragma unroll
  for (int mi = 0; mi < 4; mi++)
#pragma unroll
    for (int r = 0; r < 4; r++) {
      int rowl = wr * 64 + mi * 16 + qd * 4 + r;
      if (mt * 128 + rowl < count) {
        float* dst = y_sorted + (size_t)(hb + mt * 128 + rowl) * D_DIM
                   + nb * 128 + wc * 64 + l16;
#pragma unroll
        for (int nj = 0; nj < 4; nj++)
          dst[nj * 16] = acc[mi][nj][r];
      }
    }
}

// ---------------- combine: y[t] = ys[row(t,0)] + ys[row(t,1)] ------------------------
__global__ __launch_bounds__(256) void combine_kernel(
    const float* __restrict__ y_sorted, const int* __restrict__ tok2row,
    float* __restrict__ outY) {
  int t = blockIdx.x;
  int r0 = tok2row[t * 2], r1 = tok2row[t * 2 + 1];
  int i = threadIdx.x * 8;
  const floatx4* a = (const floatx4*)(y_sorted + (size_t)r0 * D_DIM + i);
  const floatx4* b = (const floatx4*)(y_sorted + (size_t)r1 * D_DIM + i);
  floatx4* o = (floatx4*)(outY + (size_t)t * D_DIM + i);
  o[0] = a[0] + b[0];
  o[1] = a[1] + b[1];
}

extern "C" void kernel_launch(void* const* d_in, const int* in_sizes, int n_in,
                              void* d_out, int out_size, void* d_ws, size_t ws_size,
                              hipStream_t stream) {
  (void)in_sizes; (void)n_in; (void)out_size; (void)ws_size;
  const float* hidden = (const float*)d_in[0];
  const float* gate_w = (const float*)d_in[1];
  const float* w_gate = (const float*)d_in[2];
  const float* w_up   = (const float*)d_in[3];
  const float* w_down = (const float*)d_in[4];
  float* out = (float*)d_out;
  float* outY = out;                                   // [T, D]
  float* outLogits = out + (size_t)T_TOK * D_DIM;      // [T, E]

  char* ws = (char*)d_ws;
  size_t off = 0;
  int* counts = (int*)(ws + off); off += 256;
  int* tok_ids = (int*)(ws + off); off += (size_t)N_EXP * T_TOK * 4;
  float* tok_wts = (float*)(ws + off); off += (size_t)N_EXP * T_TOK * 4;
  int* tok2row = (int*)(ws + off); off += (size_t)T_TOK * 2 * 4;
  short* x_bf = (short*)(ws + off); off += (size_t)T_TOK * D_DIM * 2;
  short* pwg = (short*)(ws + off); off += (size_t)N_EXP * F_DIM * D_DIM * 2;
  short* pwu = (short*)(ws + off); off += (size_t)N_EXP * F_DIM * D_DIM * 2;
  short* pwd = (short*)(ws + off); off += (size_t)N_EXP * D_DIM * F_DIM * 2;
  short* h_sorted = (short*)(ws + off); off += (size_t)T_TOK * 2 * F_DIM * 2;
  float* y_sorted = (float*)(ws + off); off += (size_t)T_TOK * 2 * D_DIM * 4;

  hipMemsetAsync(counts, 0, 256, stream);

  pack_wgwu<<<dim3(16, 32, N_EXP), 256, 0, stream>>>(w_gate, pwg);
  pack_wgwu<<<dim3(16, 32, N_EXP), 256, 0, stream>>>(w_up, pwu);
  pack_wd<<<dim3(16, 16, N_EXP), 256, 0, stream>>>(w_down, pwd);

  router_kernel<<<T_TOK, 256, 0, stream>>>(hidden, gate_w, x_bf, outLogits,
                                           counts, tok_ids, tok_wts);
  tok2row_kernel<<<1, 256, 0, stream>>>(counts, tok_ids, tok2row);

  gemm1_kernel<<<dim3(N_EXP * 16 * 16), 256, 0, stream>>>(
      x_bf, pwg, pwu, counts, tok_ids, tok_wts, h_sorted);

  gemm2_kernel<<<dim3(N_EXP * 16 * 16), 256, 0, stream>>>(
      h_sorted, pwd, counts, y_sorted);

  combine_kernel<<<T_TOK, 256, 0, stream>>>(y_sorted, tok2row, outY);
}

// Round 2
// 440.039 us; speedup vs baseline: 1.0995x; 1.0172x over previous
//
#include <hip/hip_runtime.h>
#include <hip/hip_bf16.h>

#define T_TOK 2048
#define D_DIM 2048
#define N_EXP 8
#define F_DIM 1024
#define MAX_TILES 40

typedef __attribute__((ext_vector_type(8))) short short8;
typedef __attribute__((ext_vector_type(4))) float floatx4;

__device__ __forceinline__ short f2bf(float f) {
  union { float f; unsigned u; } v; v.f = f;
  unsigned r = v.u + 0x7fffu + ((v.u >> 16) & 1u);
  return (short)(r >> 16);
}

__device__ __forceinline__ floatx4 mfma16(short8 a, short8 b, floatx4 c) {
  return __builtin_amdgcn_mfma_f32_16x16x32_bf16(a, b, c, 0, 0, 0);
}

__device__ __forceinline__ void gload16(const void* g, void* l) {
  __builtin_amdgcn_global_load_lds(
      (const __attribute__((address_space(1))) unsigned int*)g,
      (__attribute__((address_space(3))) unsigned int*)l, 16, 0, 0);
}

// ---- transpose+cvt+PACK wg/wu: [E][D][F] -> pw[((e*16+fb)*32+s)*4096 + r*64 + c]
// (fb = f>>6, r = f&63, s = d>>6, c = d&63) : each (fb,s) chunk is 8KB contiguous.
__global__ __launch_bounds__(256) void pack_wgwu(const float* __restrict__ src,
                                                 short* __restrict__ dst) {
  int fb = blockIdx.x, s = blockIdx.y, e = blockIdx.z;
  __shared__ float tile[64][65];   // [d-local][f-local]
  int tx = threadIdx.x & 63, ty = threadIdx.x >> 6;
  const float* sp = src + (size_t)e * D_DIM * F_DIM + (size_t)(s * 64) * F_DIM + fb * 64;
#pragma unroll
  for (int i = 0; i < 64; i += 4)
    tile[ty + i][tx] = sp[(size_t)(ty + i) * F_DIM + tx];
  __syncthreads();
  short* dp = dst + (size_t)((e * 16 + fb) * 32 + s) * 4096;
#pragma unroll
  for (int i = 0; i < 64; i += 4)
    dp[(ty + i) * 64 + tx] = f2bf(tile[tx][ty + i]);   // dst[r][c] = src(d=s64+c, f=fb64+r)
}

// ---- transpose+cvt+PACK wd: [E][F][D] -> pw[((e*16+nb)*16+s)*8192 + r*64 + c]
// (nb = d>>7, r = d&127, s = f>>6, c = f&63) : each (nb,s) chunk is 16KB contiguous.
__global__ __launch_bounds__(256) void pack_wd(const float* __restrict__ src,
                                               short* __restrict__ dst) {
  int nb = blockIdx.x, s = blockIdx.y, e = blockIdx.z;
  __shared__ float tile[64][129];  // [k-local][n-local]
  int tx2 = threadIdx.x & 127, ty2 = threadIdx.x >> 7;
  const float* sp = src + (size_t)e * F_DIM * D_DIM + (size_t)(s * 64) * D_DIM + nb * 128;
#pragma unroll
  for (int i = 0; i < 64; i += 2)
    tile[ty2 + i][tx2] = sp[(size_t)(ty2 + i) * D_DIM + tx2];
  __syncthreads();
  int tx = threadIdx.x & 63, ty = threadIdx.x >> 6;
  short* dp = dst + (size_t)((e * 16 + nb) * 16 + s) * 8192;
#pragma unroll
  for (int r = 0; r < 128; r += 4)
    dp[(r + ty) * 64 + tx] = f2bf(tile[tx][r + ty]);   // dst[r][c] = src(f=s64+c, d=nb128+r)
}

// ---------------- router: logits (fp32), top-2, expert lists, x -> bf16 --------------
__global__ __launch_bounds__(256) void router_kernel(
    const float* __restrict__ x, const float* __restrict__ gate_w,
    short* __restrict__ x_bf, float* __restrict__ out_logits,
    int* __restrict__ counts, int* __restrict__ tok_ids, float* __restrict__ tok_wts) {
  int t = blockIdx.x;
  int tid = threadIdx.x;
  const float* xr = x + (size_t)t * D_DIM + tid * 8;
  floatx4 xv0 = *(const floatx4*)xr;
  floatx4 xv1 = *(const floatx4*)(xr + 4);
  float xs[8];
#pragma unroll
  for (int j = 0; j < 4; j++) { xs[j] = xv0[j]; xs[4 + j] = xv1[j]; }
  union { short8 v; short s[8]; } xb;
#pragma unroll
  for (int j = 0; j < 8; j++) xb.s[j] = f2bf(xs[j]);
  *(short8*)(x_bf + (size_t)t * D_DIM + tid * 8) = xb.v;

  float p[N_EXP];
#pragma unroll
  for (int e = 0; e < N_EXP; e++) {
    const float* gw = gate_w + (size_t)e * D_DIM + tid * 8;
    floatx4 g0 = *(const floatx4*)gw;
    floatx4 g1 = *(const floatx4*)(gw + 4);
    float s = 0.f;
#pragma unroll
    for (int j = 0; j < 4; j++) s += xs[j] * g0[j] + xs[4 + j] * g1[j];
    p[e] = s;
  }
  __shared__ float red[N_EXP * 4];
  __shared__ float slog[N_EXP];
  int lane = tid & 63, wv = tid >> 6;
#pragma unroll
  for (int e = 0; e < N_EXP; e++) {
    float v = p[e];
#pragma unroll
    for (int off = 32; off > 0; off >>= 1) v += __shfl_down(v, off);
    if (lane == 0) red[e * 4 + wv] = v;
  }
  __syncthreads();
  if (tid < N_EXP) {
    float s = red[tid * 4] + red[tid * 4 + 1] + red[tid * 4 + 2] + red[tid * 4 + 3];
    slog[tid] = s;
    out_logits[(size_t)t * N_EXP + tid] = s;
  }
  __syncthreads();
  if (tid == 0) {
    float l[N_EXP];
#pragma unroll
    for (int e = 0; e < N_EXP; e++) l[e] = slog[e];
    int e0 = 0;
#pragma unroll
    for (int e = 1; e < N_EXP; e++) if (l[e] > l[e0]) e0 = e;
    int e1 = (e0 == 0) ? 1 : 0;
#pragma unroll
    for (int e = 0; e < N_EXP; e++) if (e != e0 && l[e] > l[e1]) e1 = e;
    float p1 = __expf(l[e1] - l[e0]);
    float s = 1.f + p1;
    int pos0 = atomicAdd(&counts[e0], 1);
    tok_ids[e0 * T_TOK + pos0] = t;             // k = 0
    tok_wts[e0 * T_TOK + pos0] = 1.f / s;
    int pos1 = atomicAdd(&counts[e1], 1);
    tok_ids[e1 * T_TOK + pos1] = t | (1 << 16); // k = 1
    tok_wts[e1 * T_TOK + pos1] = p1 / s;
  }
}

// ---------------- tok2row: inverse map + dense tile work-list ------------------------
__global__ __launch_bounds__(256) void tok2row_kernel(
    const int* __restrict__ counts, const int* __restrict__ tok_ids,
    int* __restrict__ tok2row, int* __restrict__ wk, int* __restrict__ ntiles) {
  int tid = threadIdx.x;
  int base = 0;
  for (int e = 0; e < N_EXP; e++) {
    int c = counts[e];
    for (int pos = tid; pos < c; pos += 256) {
      int raw = tok_ids[e * T_TOK + pos];
      tok2row[(raw & 0xFFFF) * 2 + (raw >> 16)] = base + pos;
    }
    base += c;
  }
  if (tid == 0) {
    // dense work-list: only tiles that exist, so GEMM grids have no holes
    int nt = 0;
    for (int e = 0; e < N_EXP; e++) {
      int c = counts[e];
      int nti = (c + 127) >> 7;
      for (int m = 0; m < nti; m++) { wk[nt] = e | (m << 8); nt++; }
    }
    ntiles[0] = nt;
  }
}

// ---------------- GEMM1: 128M x 64N, BK=64, dbuf pipeline, dense grid ----------------
// grid (16 fb, MAX_TILES t); lin = fb + 16*t -> XCD = fb&7 (B-chunk (e,fb) readers
// all co-XCD); active blocks are a dense prefix in t -> even CU fill, no dispatch holes.
__global__ __launch_bounds__(256, 2) void gemm1_kernel(
    const short* __restrict__ x_bf,
    const short* __restrict__ pwg, const short* __restrict__ pwu,
    const int* __restrict__ counts, const int* __restrict__ tok_ids,
    const float* __restrict__ tok_wts,
    const int* __restrict__ wk, const int* __restrict__ ntiles,
    short* __restrict__ h_sorted) {
  int t = blockIdx.y;
  if (t >= ntiles[0]) return;
  int w  = wk[t];
  int e  = w & 255;
  int mt = w >> 8;
  int fb = blockIdx.x;
  int count = counts[e];
  int hb = 0;
#pragma unroll
  for (int i = 0; i < N_EXP; i++) { int c = counts[i]; if (i < e) hb += c; }

  __shared__ short sA[2][8192];    // 2 x (128 x 64)
  __shared__ short sBg[2][4096];   // 2 x (64 x 64)
  __shared__ short sBu[2][4096];   // exactly 64KB total

  int tid = threadIdx.x;
  int lane = tid & 63, wv = tid >> 6;
  int wr = wv >> 1, wc = wv & 1;
  int l16 = lane & 15, qd = lane >> 4;
  int lr = lane >> 3, lc = lane & 7;
  int csw8 = (lc ^ lr) * 8;   // XOR swizzle: LDS[row][pos] holds chunk pos^(row&7)

  int offA[4], offB[2];
#pragma unroll
  for (int it = 0; it < 4; it++) {
    int r = wv * 32 + it * 8 + lr;
    int raw = (mt * 128 + r < count) ? tok_ids[e * T_TOK + mt * 128 + r] : 0;
    offA[it] = (raw & 0xFFFF) * D_DIM + csw8;
  }
#pragma unroll
  for (int it = 0; it < 2; it++)
    offB[it] = (wv * 16 + it * 8 + lr) * 64 + csw8;   // within packed 8KB chunk
  const short* pBg = pwg + (size_t)((e * 16 + fb) * 32) * 4096;
  const short* pBu = pwu + (size_t)((e * 16 + fb) * 32) * 4096;

  floatx4 accG[4][2] = {};
  floatx4 accU[4][2] = {};
  int sw = l16 & 7;
  int rAo  = (wr * 64 + l16) * 64;
  int rBo  = (wc * 32 + l16) * 64;

  // prologue: stage tile 0 into buffer 0
#pragma unroll
  for (int it = 0; it < 4; it++)
    gload16(x_bf + offA[it], &sA[0][wv * 2048 + it * 512]);
#pragma unroll
  for (int it = 0; it < 2; it++) {
    gload16(pBg + offB[it], &sBg[0][wv * 1024 + it * 512]);
    gload16(pBu + offB[it], &sBu[0][wv * 1024 + it * 512]);
  }

  int cur = 0;
  for (int s = 0; s < D_DIM / 64; s++) {
    __syncthreads();   // drains vmcnt: buf[cur] staged; buf[cur^1] free to overwrite
    if (s + 1 < D_DIM / 64) {
      int nxt = cur ^ 1;
#pragma unroll
      for (int it = 0; it < 4; it++)
        gload16(x_bf + offA[it] + (s + 1) * 64, &sA[nxt][wv * 2048 + it * 512]);
#pragma unroll
      for (int it = 0; it < 2; it++) {
        gload16(pBg + (size_t)(s + 1) * 4096 + offB[it], &sBg[nxt][wv * 1024 + it * 512]);
        gload16(pBu + (size_t)(s + 1) * 4096 + offB[it], &sBu[nxt][wv * 1024 + it * 512]);
      }
    }
    const short* rA  = &sA[cur][rAo];
    const short* rBg = &sBg[cur][rBo];
    const short* rBu = &sBu[cur][rBo];
#pragma unroll
    for (int kk = 0; kk < 2; kk++) {
      short8 a[4], bg[2], bu[2];
      int c = ((kk * 4 + qd) ^ sw) * 8;
#pragma unroll
      for (int mi = 0; mi < 4; mi++) a[mi] = *(const short8*)(rA + mi * 16 * 64 + c);
#pragma unroll
      for (int nj = 0; nj < 2; nj++) {
        bg[nj] = *(const short8*)(rBg + nj * 16 * 64 + c);
        bu[nj] = *(const short8*)(rBu + nj * 16 * 64 + c);
      }
#pragma unroll
      for (int mi = 0; mi < 4; mi++)
#pragma unroll
        for (int nj = 0; nj < 2; nj++) {
          accG[mi][nj] = mfma16(a[mi], bg[nj], accG[mi][nj]);
          accU[mi][nj] = mfma16(a[mi], bu[nj], accU[mi][nj]);
        }
    }
    cur ^= 1;
  }

#pragma unroll
  for (int mi = 0; mi < 4; mi++)
#pragma unroll
    for (int r = 0; r < 4; r++) {
      int rowl = wr * 64 + mi * 16 + qd * 4 + r;
      if (mt * 128 + rowl < count) {
        float wt = tok_wts[e * T_TOK + mt * 128 + rowl];
        short* hdst = h_sorted + (size_t)(hb + mt * 128 + rowl) * F_DIM
                    + fb * 64 + wc * 32 + l16;
#pragma unroll
        for (int nj = 0; nj < 2; nj++) {
          float g = accG[mi][nj][r], u = accU[mi][nj][r];
          float sg = g / (1.f + __expf(-g));
          hdst[nj * 16] = f2bf(sg * u * wt);
        }
      }
    }
}

// ---------------- GEMM2: 128x128, BK=64, dbuf pipeline, dense grid -------------------
__global__ __launch_bounds__(256, 2) void gemm2_kernel(
    const short* __restrict__ h_sorted, const short* __restrict__ pwd,
    const int* __restrict__ counts,
    const int* __restrict__ wk, const int* __restrict__ ntiles,
    float* __restrict__ y_sorted) {
  int t = blockIdx.y;
  if (t >= ntiles[0]) return;
  int w  = wk[t];
  int e  = w & 255;
  int mt = w >> 8;
  int nb = blockIdx.x;
  int count = counts[e];
  int hb = 0;
#pragma unroll
  for (int i = 0; i < N_EXP; i++) { int c = counts[i]; if (i < e) hb += c; }

  __shared__ short sA[2][8192];
  __shared__ short sB[2][8192];   // exactly 64KB total

  int tid = threadIdx.x;
  int lane = tid & 63, wv = tid >> 6;
  int wr = wv >> 1, wc = wv & 1;
  int l16 = lane & 15, qd = lane >> 4;
  int lr = lane >> 3, lc = lane & 7;
  int csw8 = (lc ^ lr) * 8;

  int offA[4], offB[4];
#pragma unroll
  for (int it = 0; it < 4; it++) {
    int r = wv * 32 + it * 8 + lr;
    offA[it] = (hb + mt * 128 + r) * F_DIM + csw8;     // contiguous sorted rows
    offB[it] = r * 64 + csw8;                          // within packed 16KB chunk
  }
  const short* pB = pwd + (size_t)((e * 16 + nb) * 16) * 8192;

  floatx4 acc[4][4] = {};
  int sw = l16 & 7;
  int rAo = (wr * 64 + l16) * 64;
  int rBo = (wc * 64 + l16) * 64;

  // prologue: stage tile 0 into buffer 0
#pragma unroll
  for (int it = 0; it < 4; it++) {
    gload16(h_sorted + offA[it], &sA[0][wv * 2048 + it * 512]);
    gload16(pB + offB[it], &sB[0][wv * 2048 + it * 512]);
  }

  int cur = 0;
  for (int s = 0; s < F_DIM / 64; s++) {
    __syncthreads();
    if (s + 1 < F_DIM / 64) {
      int nxt = cur ^ 1;
#pragma unroll
      for (int it = 0; it < 4; it++) {
        gload16(h_sorted + offA[it] + (s + 1) * 64, &sA[nxt][wv * 2048 + it * 512]);
        gload16(pB + (size_t)(s + 1) * 8192 + offB[it], &sB[nxt][wv * 2048 + it * 512]);
      }
    }
    const short* rA = &sA[cur][rAo];
    const short* rB = &sB[cur][rBo];
#pragma unroll
    for (int kk = 0; kk < 2; kk++) {
      short8 a[4], b[4];
      int c = ((kk * 4 + qd) ^ sw) * 8;
#pragma unroll
      for (int mi = 0; mi < 4; mi++) a[mi] = *(const short8*)(rA + mi * 16 * 64 + c);
#pragma unroll
      for (int nj = 0; nj < 4; nj++) b[nj] = *(const short8*)(rB + nj * 16 * 64 + c);
#pragma unroll
      for (int mi = 0; mi < 4; mi++)
#pragma unroll
        for (int nj = 0; nj < 4; nj++)
          acc[mi][nj] = mfma16(a[mi], b[nj], acc[mi][nj]);
    }
    cur ^= 1;
  }

#pragma unroll
  for (int mi = 0; mi < 4; mi++)
#pragma unroll
    for (int r = 0; r < 4; r++) {
      int rowl = wr * 64 + mi * 16 + qd * 4 + r;
      if (mt * 128 + rowl < count) {
        float* dst = y_sorted + (size_t)(hb + mt * 128 + rowl) * D_DIM
                   + nb * 128 + wc * 64 + l16;
#pragma unroll
        for (int nj = 0; nj < 4; nj++)
          dst[nj * 16] = acc[mi][nj][r];
      }
    }
}

// ---------------- combine: y[t] = ys[row(t,0)] + ys[row(t,1)] ------------------------
__global__ __launch_bounds__(256) void combine_kernel(
    const float* __restrict__ y_sorted, const int* __restrict__ tok2row,
    float* __restrict__ outY) {
  int t = blockIdx.x;
  int r0 = tok2row[t * 2], r1 = tok2row[t * 2 + 1];
  int i = threadIdx.x * 8;
  const floatx4* a = (const floatx4*)(y_sorted + (size_t)r0 * D_DIM + i);
  const floatx4* b = (const floatx4*)(y_sorted + (size_t)r1 * D_DIM + i);
  floatx4* o = (floatx4*)(outY + (size_t)t * D_DIM + i);
  o[0] = a[0] + b[0];
  o[1] = a[1] + b[1];
}

extern "C" void kernel_launch(void* const* d_in, const int* in_sizes, int n_in,
                              void* d_out, int out_size, void* d_ws, size_t ws_size,
                              hipStream_t stream) {
  (void)in_sizes; (void)n_in; (void)out_size; (void)ws_size;
  const float* hidden = (const float*)d_in[0];
  const float* gate_w = (const float*)d_in[1];
  const float* w_gate = (const float*)d_in[2];
  const float* w_up   = (const float*)d_in[3];
  const float* w_down = (const float*)d_in[4];
  float* out = (float*)d_out;
  float* outY = out;                                   // [T, D]
  float* outLogits = out + (size_t)T_TOK * D_DIM;      // [T, E]

  char* ws = (char*)d_ws;
  size_t off = 0;
  int* counts = (int*)(ws + off); off += 256;
  int* wk = (int*)(ws + off); off += MAX_TILES * 4;
  int* ntiles = (int*)(ws + off); off += 64;
  int* tok_ids = (int*)(ws + off); off += (size_t)N_EXP * T_TOK * 4;
  float* tok_wts = (float*)(ws + off); off += (size_t)N_EXP * T_TOK * 4;
  int* tok2row = (int*)(ws + off); off += (size_t)T_TOK * 2 * 4;
  short* x_bf = (short*)(ws + off); off += (size_t)T_TOK * D_DIM * 2;
  short* pwg = (short*)(ws + off); off += (size_t)N_EXP * F_DIM * D_DIM * 2;
  short* pwu = (short*)(ws + off); off += (size_t)N_EXP * F_DIM * D_DIM * 2;
  short* pwd = (short*)(ws + off); off += (size_t)N_EXP * D_DIM * F_DIM * 2;
  short* h_sorted = (short*)(ws + off); off += (size_t)T_TOK * 2 * F_DIM * 2;
  float* y_sorted = (float*)(ws + off); off += (size_t)T_TOK * 2 * D_DIM * 4;

  hipMemsetAsync(counts, 0, 256, stream);

  pack_wgwu<<<dim3(16, 32, N_EXP), 256, 0, stream>>>(w_gate, pwg);
  pack_wgwu<<<dim3(16, 32, N_EXP), 256, 0, stream>>>(w_up, pwu);
  pack_wd<<<dim3(16, 16, N_EXP), 256, 0, stream>>>(w_down, pwd);

  router_kernel<<<T_TOK, 256, 0, stream>>>(hidden, gate_w, x_bf, outLogits,
                                           counts, tok_ids, tok_wts);
  tok2row_kernel<<<1, 256, 0, stream>>>(counts, tok_ids, tok2row, wk, ntiles);

  gemm1_kernel<<<dim3(16, MAX_TILES), 256, 0, stream>>>(
      x_bf, pwg, pwu, counts, tok_ids, tok_wts, wk, ntiles, h_sorted);

  gemm2_kernel<<<dim3(16, MAX_TILES), 256, 0, stream>>>(
      h_sorted, pwd, counts, wk, ntiles, y_sorted);

  combine_kernel<<<T_TOK, 256, 0, stream>>>(y_sorted, tok2row, outY);
}

// Round 3
// 424.304 us; speedup vs baseline: 1.1403x; 1.0371x over previous
//
#include <hip/hip_runtime.h>
#include <hip/hip_bf16.h>

#define T_TOK 2048
#define D_DIM 2048
#define N_EXP 8
#define F_DIM 1024
#define MAX_TILES 40

typedef __attribute__((ext_vector_type(8))) short short8;
typedef __attribute__((ext_vector_type(4))) float floatx4;

#define SCHED_FENCE() __builtin_amdgcn_sched_barrier(0)
#define BARRIER() __builtin_amdgcn_s_barrier()
#define WAIT_VM8() asm volatile("s_waitcnt vmcnt(8)" ::: "memory")
#define WAIT_VM0() asm volatile("s_waitcnt vmcnt(0)" ::: "memory")
#define WAIT_LGKM0() asm volatile("s_waitcnt lgkmcnt(0)" ::: "memory")

__device__ __forceinline__ short f2bf(float f) {
  union { float f; unsigned u; } v; v.f = f;
  unsigned r = v.u + 0x7fffu + ((v.u >> 16) & 1u);
  return (short)(r >> 16);
}

__device__ __forceinline__ floatx4 mfma16(short8 a, short8 b, floatx4 c) {
  return __builtin_amdgcn_mfma_f32_16x16x32_bf16(a, b, c, 0, 0, 0);
}

__device__ __forceinline__ void gload16(const void* g, void* l) {
  __builtin_amdgcn_global_load_lds(
      (const __attribute__((address_space(1))) unsigned int*)g,
      (__attribute__((address_space(3))) unsigned int*)l, 16, 0, 0);
}

// ---- transpose+cvt+PACK wg/wu: [E][D][F] -> pw[((e*16+fb)*32+s)*4096 + r*64 + c]
// (fb = f>>6, r = f&63, s = d>>6, c = d&63) : each (fb,s) chunk is 8KB contiguous.
__global__ __launch_bounds__(256) void pack_wgwu(const float* __restrict__ src,
                                                 short* __restrict__ dst) {
  int fb = blockIdx.x, s = blockIdx.y, e = blockIdx.z;
  __shared__ float tile[64][65];   // [d-local][f-local]
  int tx = threadIdx.x & 63, ty = threadIdx.x >> 6;
  const float* sp = src + (size_t)e * D_DIM * F_DIM + (size_t)(s * 64) * F_DIM + fb * 64;
#pragma unroll
  for (int i = 0; i < 64; i += 4)
    tile[ty + i][tx] = sp[(size_t)(ty + i) * F_DIM + tx];
  __syncthreads();
  short* dp = dst + (size_t)((e * 16 + fb) * 32 + s) * 4096;
#pragma unroll
  for (int i = 0; i < 64; i += 4)
    dp[(ty + i) * 64 + tx] = f2bf(tile[tx][ty + i]);   // dst[r][c] = src(d=s64+c, f=fb64+r)
}

// ---- transpose+cvt+PACK wd: [E][F][D] -> pw[((e*16+nb)*16+s)*8192 + r*64 + c]
// (nb = d>>7, r = d&127, s = f>>6, c = f&63) : each (nb,s) chunk is 16KB contiguous.
__global__ __launch_bounds__(256) void pack_wd(const float* __restrict__ src,
                                               short* __restrict__ dst) {
  int nb = blockIdx.x, s = blockIdx.y, e = blockIdx.z;
  __shared__ float tile[64][129];  // [k-local][n-local]
  int tx2 = threadIdx.x & 127, ty2 = threadIdx.x >> 7;
  const float* sp = src + (size_t)e * F_DIM * D_DIM + (size_t)(s * 64) * D_DIM + nb * 128;
#pragma unroll
  for (int i = 0; i < 64; i += 2)
    tile[ty2 + i][tx2] = sp[(size_t)(ty2 + i) * D_DIM + tx2];
  __syncthreads();
  int tx = threadIdx.x & 63, ty = threadIdx.x >> 6;
  short* dp = dst + (size_t)((e * 16 + nb) * 16 + s) * 8192;
#pragma unroll
  for (int r = 0; r < 128; r += 4)
    dp[(r + ty) * 64 + tx] = f2bf(tile[tx][r + ty]);   // dst[r][c] = src(f=s64+c, d=nb128+r)
}

// ---------------- router: logits (fp32), top-2, expert lists, x -> bf16 --------------
__global__ __launch_bounds__(256) void router_kernel(
    const float* __restrict__ x, const float* __restrict__ gate_w,
    short* __restrict__ x_bf, float* __restrict__ out_logits,
    int* __restrict__ counts, int* __restrict__ tok_ids, float* __restrict__ tok_wts) {
  int t = blockIdx.x;
  int tid = threadIdx.x;
  const float* xr = x + (size_t)t * D_DIM + tid * 8;
  floatx4 xv0 = *(const floatx4*)xr;
  floatx4 xv1 = *(const floatx4*)(xr + 4);
  float xs[8];
#pragma unroll
  for (int j = 0; j < 4; j++) { xs[j] = xv0[j]; xs[4 + j] = xv1[j]; }
  union { short8 v; short s[8]; } xb;
#pragma unroll
  for (int j = 0; j < 8; j++) xb.s[j] = f2bf(xs[j]);
  *(short8*)(x_bf + (size_t)t * D_DIM + tid * 8) = xb.v;

  float p[N_EXP];
#pragma unroll
  for (int e = 0; e < N_EXP; e++) {
    const float* gw = gate_w + (size_t)e * D_DIM + tid * 8;
    floatx4 g0 = *(const floatx4*)gw;
    floatx4 g1 = *(const floatx4*)(gw + 4);
    float s = 0.f;
#pragma unroll
    for (int j = 0; j < 4; j++) s += xs[j] * g0[j] + xs[4 + j] * g1[j];
    p[e] = s;
  }
  __shared__ float red[N_EXP * 4];
  __shared__ float slog[N_EXP];
  int lane = tid & 63, wv = tid >> 6;
#pragma unroll
  for (int e = 0; e < N_EXP; e++) {
    float v = p[e];
#pragma unroll
    for (int off = 32; off > 0; off >>= 1) v += __shfl_down(v, off);
    if (lane == 0) red[e * 4 + wv] = v;
  }
  __syncthreads();
  if (tid < N_EXP) {
    float s = red[tid * 4] + red[tid * 4 + 1] + red[tid * 4 + 2] + red[tid * 4 + 3];
    slog[tid] = s;
    out_logits[(size_t)t * N_EXP + tid] = s;
  }
  __syncthreads();
  if (tid == 0) {
    float l[N_EXP];
#pragma unroll
    for (int e = 0; e < N_EXP; e++) l[e] = slog[e];
    int e0 = 0;
#pragma unroll
    for (int e = 1; e < N_EXP; e++) if (l[e] > l[e0]) e0 = e;
    int e1 = (e0 == 0) ? 1 : 0;
#pragma unroll
    for (int e = 0; e < N_EXP; e++) if (e != e0 && l[e] > l[e1]) e1 = e;
    float p1 = __expf(l[e1] - l[e0]);
    float s = 1.f + p1;
    int pos0 = atomicAdd(&counts[e0], 1);
    tok_ids[e0 * T_TOK + pos0] = t;             // k = 0
    tok_wts[e0 * T_TOK + pos0] = 1.f / s;
    int pos1 = atomicAdd(&counts[e1], 1);
    tok_ids[e1 * T_TOK + pos1] = t | (1 << 16); // k = 1
    tok_wts[e1 * T_TOK + pos1] = p1 / s;
  }
}

// ---------------- tok2row: inverse map + dense tile work-list ------------------------
__global__ __launch_bounds__(256) void tok2row_kernel(
    const int* __restrict__ counts, const int* __restrict__ tok_ids,
    int* __restrict__ tok2row, int* __restrict__ wk, int* __restrict__ ntiles) {
  int tid = threadIdx.x;
  int base = 0;
  for (int e = 0; e < N_EXP; e++) {
    int c = counts[e];
    for (int pos = tid; pos < c; pos += 256) {
      int raw = tok_ids[e * T_TOK + pos];
      tok2row[(raw & 0xFFFF) * 2 + (raw >> 16)] = base + pos;
    }
    base += c;
  }
  if (tid == 0) {
    // dense work-list: only tiles that exist, so GEMM grids have no holes
    int nt = 0;
    for (int e = 0; e < N_EXP; e++) {
      int c = counts[e];
      int nti = (c + 127) >> 7;
      for (int m = 0; m < nti; m++) { wk[nt] = e | (m << 8); nt++; }
    }
    ntiles[0] = nt;
  }
}

// ---------------- GEMM1: 128M x 64N, BK=64, counted-vmcnt dbuf pipeline --------------
// Two barriers/iter, NEVER vmcnt(0) mid-loop: prefetch for tile s+1 is issued BEFORE
// waiting on tile-s loads (vmcnt(8) = keep the 8 newest in flight), so each tile's
// loads get a full iteration of latency cover (T3/T4, m218).
__global__ __launch_bounds__(256, 2) void gemm1_kernel(
    const short* __restrict__ x_bf,
    const short* __restrict__ pwg, const short* __restrict__ pwu,
    const int* __restrict__ counts, const int* __restrict__ tok_ids,
    const float* __restrict__ tok_wts,
    const int* __restrict__ wk, const int* __restrict__ ntiles,
    short* __restrict__ h_sorted) {
  int t = blockIdx.y;
  if (t >= ntiles[0]) return;
  int w  = wk[t];
  int e  = w & 255;
  int mt = w >> 8;
  int fb = blockIdx.x;
  int count = counts[e];
  int hb = 0;
#pragma unroll
  for (int i = 0; i < N_EXP; i++) { int c = counts[i]; if (i < e) hb += c; }

  __shared__ short sA[2][8192];    // 2 x (128 x 64)
  __shared__ short sBg[2][4096];   // 2 x (64 x 64)
  __shared__ short sBu[2][4096];   // exactly 64KB total

  int tid = threadIdx.x;
  int lane = tid & 63, wv = tid >> 6;
  int wr = wv >> 1, wc = wv & 1;
  int l16 = lane & 15, qd = lane >> 4;
  int lr = lane >> 3, lc = lane & 7;
  int csw8 = (lc ^ lr) * 8;   // XOR swizzle: LDS[row][pos] holds chunk pos^(row&7)

  int offA[4], offB[2];
#pragma unroll
  for (int it = 0; it < 4; it++) {
    int r = wv * 32 + it * 8 + lr;
    int raw = (mt * 128 + r < count) ? tok_ids[e * T_TOK + mt * 128 + r] : 0;
    offA[it] = (raw & 0xFFFF) * D_DIM + csw8;
  }
#pragma unroll
  for (int it = 0; it < 2; it++)
    offB[it] = (wv * 16 + it * 8 + lr) * 64 + csw8;   // within packed 8KB chunk
  const short* pBg = pwg + (size_t)((e * 16 + fb) * 32) * 4096;
  const short* pBu = pwu + (size_t)((e * 16 + fb) * 32) * 4096;

  floatx4 accG[4][2] = {};
  floatx4 accU[4][2] = {};
  int sw = l16 & 7;
  int rAo  = (wr * 64 + l16) * 64;
  int rBo  = (wc * 32 + l16) * 64;

  // prologue: stage tile 0 into buffer 0 (8 loads/wave)
#pragma unroll
  for (int it = 0; it < 4; it++)
    gload16(x_bf + offA[it], &sA[0][wv * 2048 + it * 512]);
#pragma unroll
  for (int it = 0; it < 2; it++) {
    gload16(pBg + offB[it], &sBg[0][wv * 1024 + it * 512]);
    gload16(pBu + offB[it], &sBu[0][wv * 1024 + it * 512]);
  }

  const int NS = D_DIM / 64;
  int cur = 0;
  for (int s = 0; s < NS; s++) {
    int nxt = cur ^ 1;
    if (s + 1 < NS) {
      // issue prefetch for tile s+1 (buf[nxt] freed by barrier-2 of iter s-1)
#pragma unroll
      for (int it = 0; it < 4; it++)
        gload16(x_bf + offA[it] + (s + 1) * 64, &sA[nxt][wv * 2048 + it * 512]);
#pragma unroll
      for (int it = 0; it < 2; it++) {
        gload16(pBg + (size_t)(s + 1) * 4096 + offB[it], &sBg[nxt][wv * 1024 + it * 512]);
        gload16(pBu + (size_t)(s + 1) * 4096 + offB[it], &sBu[nxt][wv * 1024 + it * 512]);
      }
      SCHED_FENCE();
      WAIT_VM8();                    // tile-s loads done; tile-(s+1) stays in flight
    } else {
      WAIT_VM0();                    // epilogue: drain the final tile
    }
    BARRIER();                       // all waves: buf[cur] fully staged
    SCHED_FENCE();
    const short* rA  = &sA[cur][rAo];
    const short* rBg = &sBg[cur][rBo];
    const short* rBu = &sBu[cur][rBo];
#pragma unroll
    for (int kk = 0; kk < 2; kk++) {
      short8 a[4], bg[2], bu[2];
      int c = ((kk * 4 + qd) ^ sw) * 8;
#pragma unroll
      for (int mi = 0; mi < 4; mi++) a[mi] = *(const short8*)(rA + mi * 16 * 64 + c);
#pragma unroll
      for (int nj = 0; nj < 2; nj++) {
        bg[nj] = *(const short8*)(rBg + nj * 16 * 64 + c);
        bu[nj] = *(const short8*)(rBu + nj * 16 * 64 + c);
      }
#pragma unroll
      for (int mi = 0; mi < 4; mi++)
#pragma unroll
        for (int nj = 0; nj < 2; nj++) {
          accG[mi][nj] = mfma16(a[mi], bg[nj], accG[mi][nj]);
          accU[mi][nj] = mfma16(a[mi], bu[nj], accU[mi][nj]);
        }
    }
    WAIT_LGKM0();
    BARRIER();                       // all waves done reading buf[cur] -> freeable
    cur = nxt;
  }

#pragma unroll
  for (int mi = 0; mi < 4; mi++)
#pragma unroll
    for (int r = 0; r < 4; r++) {
      int rowl = wr * 64 + mi * 16 + qd * 4 + r;
      if (mt * 128 + rowl < count) {
        float wt = tok_wts[e * T_TOK + mt * 128 + rowl];
        short* hdst = h_sorted + (size_t)(hb + mt * 128 + rowl) * F_DIM
                    + fb * 64 + wc * 32 + l16;
#pragma unroll
        for (int nj = 0; nj < 2; nj++) {
          float g = accG[mi][nj][r], u = accU[mi][nj][r];
          float sg = g / (1.f + __expf(-g));
          hdst[nj * 16] = f2bf(sg * u * wt);
        }
      }
    }
}

// ---------------- GEMM2: 128x128, BK=64, counted-vmcnt dbuf pipeline -----------------
__global__ __launch_bounds__(256, 2) void gemm2_kernel(
    const short* __restrict__ h_sorted, const short* __restrict__ pwd,
    const int* __restrict__ counts,
    const int* __restrict__ wk, const int* __restrict__ ntiles,
    float* __restrict__ y_sorted) {
  int t = blockIdx.y;
  if (t >= ntiles[0]) return;
  int w  = wk[t];
  int e  = w & 255;
  int mt = w >> 8;
  int nb = blockIdx.x;
  int count = counts[e];
  int hb = 0;
#pragma unroll
  for (int i = 0; i < N_EXP; i++) { int c = counts[i]; if (i < e) hb += c; }

  __shared__ short sA[2][8192];
  __shared__ short sB[2][8192];   // exactly 64KB total

  int tid = threadIdx.x;
  int lane = tid & 63, wv = tid >> 6;
  int wr = wv >> 1, wc = wv & 1;
  int l16 = lane & 15, qd = lane >> 4;
  int lr = lane >> 3, lc = lane & 7;
  int csw8 = (lc ^ lr) * 8;

  int offA[4], offB[4];
#pragma unroll
  for (int it = 0; it < 4; it++) {
    int r = wv * 32 + it * 8 + lr;
    offA[it] = (hb + mt * 128 + r) * F_DIM + csw8;     // contiguous sorted rows
    offB[it] = r * 64 + csw8;                          // within packed 16KB chunk
  }
  const short* pB = pwd + (size_t)((e * 16 + nb) * 16) * 8192;

  floatx4 acc[4][4] = {};
  int sw = l16 & 7;
  int rAo = (wr * 64 + l16) * 64;
  int rBo = (wc * 64 + l16) * 64;

  // prologue: stage tile 0 into buffer 0 (8 loads/wave)
#pragma unroll
  for (int it = 0; it < 4; it++) {
    gload16(h_sorted + offA[it], &sA[0][wv * 2048 + it * 512]);
    gload16(pB + offB[it], &sB[0][wv * 2048 + it * 512]);
  }

  const int NS = F_DIM / 64;
  int cur = 0;
  for (int s = 0; s < NS; s++) {
    int nxt = cur ^ 1;
    if (s + 1 < NS) {
#pragma unroll
      for (int it = 0; it < 4; it++) {
        gload16(h_sorted + offA[it] + (s + 1) * 64, &sA[nxt][wv * 2048 + it * 512]);
        gload16(pB + (size_t)(s + 1) * 8192 + offB[it], &sB[nxt][wv * 2048 + it * 512]);
      }
      SCHED_FENCE();
      WAIT_VM8();
    } else {
      WAIT_VM0();
    }
    BARRIER();
    SCHED_FENCE();
    const short* rA = &sA[cur][rAo];
    const short* rB = &sB[cur][rBo];
#pragma unroll
    for (int kk = 0; kk < 2; kk++) {
      short8 a[4], b[4];
      int c = ((kk * 4 + qd) ^ sw) * 8;
#pragma unroll
      for (int mi = 0; mi < 4; mi++) a[mi] = *(const short8*)(rA + mi * 16 * 64 + c);
#pragma unroll
      for (int nj = 0; nj < 4; nj++) b[nj] = *(const short8*)(rB + nj * 16 * 64 + c);
#pragma unroll
      for (int mi = 0; mi < 4; mi++)
#pragma unroll
        for (int nj = 0; nj < 4; nj++)
          acc[mi][nj] = mfma16(a[mi], b[nj], acc[mi][nj]);
    }
    WAIT_LGKM0();
    BARRIER();
    cur = nxt;
  }

#pragma unroll
  for (int mi = 0; mi < 4; mi++)
#pragma unroll
    for (int r = 0; r < 4; r++) {
      int rowl = wr * 64 + mi * 16 + qd * 4 + r;
      if (mt * 128 + rowl < count) {
        float* dst = y_sorted + (size_t)(hb + mt * 128 + rowl) * D_DIM
                   + nb * 128 + wc * 64 + l16;
#pragma unroll
        for (int nj = 0; nj < 4; nj++)
          dst[nj * 16] = acc[mi][nj][r];
      }
    }
}

// ---------------- combine: y[t] = ys[row(t,0)] + ys[row(t,1)] ------------------------
__global__ __launch_bounds__(256) void combine_kernel(
    const float* __restrict__ y_sorted, const int* __restrict__ tok2row,
    float* __restrict__ outY) {
  int t = blockIdx.x;
  int r0 = tok2row[t * 2], r1 = tok2row[t * 2 + 1];
  int i = threadIdx.x * 8;
  const floatx4* a = (const floatx4*)(y_sorted + (size_t)r0 * D_DIM + i);
  const floatx4* b = (const floatx4*)(y_sorted + (size_t)r1 * D_DIM + i);
  floatx4* o = (floatx4*)(outY + (size_t)t * D_DIM + i);
  o[0] = a[0] + b[0];
  o[1] = a[1] + b[1];
}

extern "C" void kernel_launch(void* const* d_in, const int* in_sizes, int n_in,
                              void* d_out, int out_size, void* d_ws, size_t ws_size,
                              hipStream_t stream) {
  (void)in_sizes; (void)n_in; (void)out_size; (void)ws_size;
  const float* hidden = (const float*)d_in[0];
  const float* gate_w = (const float*)d_in[1];
  const float* w_gate = (const float*)d_in[2];
  const float* w_up   = (const float*)d_in[3];
  const float* w_down = (const float*)d_in[4];
  float* out = (float*)d_out;
  float* outY = out;                                   // [T, D]
  float* outLogits = out + (size_t)T_TOK * D_DIM;      // [T, E]

  char* ws = (char*)d_ws;
  size_t off = 0;
  int* counts = (int*)(ws + off); off += 256;
  int* wk = (int*)(ws + off); off += MAX_TILES * 4;
  int* ntiles = (int*)(ws + off); off += 64;
  int* tok_ids = (int*)(ws + off); off += (size_t)N_EXP * T_TOK * 4;
  float* tok_wts = (float*)(ws + off); off += (size_t)N_EXP * T_TOK * 4;
  int* tok2row = (int*)(ws + off); off += (size_t)T_TOK * 2 * 4;
  short* x_bf = (short*)(ws + off); off += (size_t)T_TOK * D_DIM * 2;
  short* pwg = (short*)(ws + off); off += (size_t)N_EXP * F_DIM * D_DIM * 2;
  short* pwu = (short*)(ws + off); off += (size_t)N_EXP * F_DIM * D_DIM * 2;
  short* pwd = (short*)(ws + off); off += (size_t)N_EXP * D_DIM * F_DIM * 2;
  short* h_sorted = (short*)(ws + off); off += (size_t)T_TOK * 2 * F_DIM * 2;
  float* y_sorted = (float*)(ws + off); off += (size_t)T_TOK * 2 * D_DIM * 4;

  hipMemsetAsync(counts, 0, 256, stream);

  pack_wgwu<<<dim3(16, 32, N_EXP), 256, 0, stream>>>(w_gate, pwg);
  pack_wgwu<<<dim3(16, 32, N_EXP), 256, 0, stream>>>(w_up, pwu);
  pack_wd<<<dim3(16, 16, N_EXP), 256, 0, stream>>>(w_down, pwd);

  router_kernel<<<T_TOK, 256, 0, stream>>>(hidden, gate_w, x_bf, outLogits,
                                           counts, tok_ids, tok_wts);
  tok2row_kernel<<<1, 256, 0, stream>>>(counts, tok_ids, tok2row, wk, ntiles);

  gemm1_kernel<<<dim3(16, MAX_TILES), 256, 0, stream>>>(
      x_bf, pwg, pwu, counts, tok_ids, tok_wts, wk, ntiles, h_sorted);

  gemm2_kernel<<<dim3(16, MAX_TILES), 256, 0, stream>>>(
      h_sorted, pwd, counts, wk, ntiles, y_sorted);

  combine_kernel<<<T_TOK, 256, 0, stream>>>(y_sorted, tok2row, outY);
}